// Round 3
// baseline (802.846 us; speedup 1.0000x reference)
//
#include <hip/hip_runtime.h>
#include <stdint.h>

typedef float f32x4 __attribute__((ext_vector_type(4)));

// ---- async global->LDS, 16B per lane; LDS dest must be wave-uniform base ----
__device__ __forceinline__ void gload_lds16(const void* g, void* l) {
  __builtin_amdgcn_global_load_lds(
      (const __attribute__((address_space(1))) unsigned int*)g,
      (__attribute__((address_space(3))) unsigned int*)l,
      16, 0, 0);
}

// =========================== amax reduction ===========================
__global__ void amax_kernel(const float* __restrict__ x, long n,
                            unsigned* __restrict__ out) {
  long tid = (long)blockIdx.x * blockDim.x + threadIdx.x;
  long stride = (long)gridDim.x * blockDim.x;
  float m = 0.0f;
  for (long i = tid * 4; i < n; i += stride * 4) {
    float4 v = *reinterpret_cast<const float4*>(x + i);
    m = fmaxf(m, fmaxf(fmaxf(fabsf(v.x), fabsf(v.y)),
                       fmaxf(fabsf(v.z), fabsf(v.w))));
  }
#pragma unroll
  for (int off = 32; off > 0; off >>= 1) m = fmaxf(m, __shfl_xor(m, off));
  __shared__ float red[4];
  int wid = threadIdx.x >> 6;
  if ((threadIdx.x & 63) == 0) red[wid] = m;
  __syncthreads();
  if (threadIdx.x == 0) {
    float mm = fmaxf(fmaxf(red[0], red[1]), fmaxf(red[2], red[3]));
    atomicMax(out, __float_as_uint(mm));  // abs fp32: uint order == float order
  }
}

// =========================== scale compute ===========================
__global__ void scale_kernel(const unsigned* __restrict__ amax_bits,
                             float* __restrict__ scales) {
  float ax = __uint_as_float(amax_bits[0]);
  float aw = __uint_as_float(amax_bits[1]);
  float sx = fmaxf(ax, 1e-12f) / 448.0f;  // IEEE div, matches reference
  float sw = fmaxf(aw, 1e-12f) / 448.0f;
  scales[0] = sx;
  scales[1] = sw;
  scales[2] = sx * sw;
}

// =========================== quantize to fp8 e4m3 ===========================
__global__ void quant_kernel(const float* __restrict__ x,
                             unsigned char* __restrict__ q, long n,
                             const float* __restrict__ scale_p) {
  const float s = scale_p[0];
  long t = (long)blockIdx.x * blockDim.x + threadIdx.x;
  long nt = (long)gridDim.x * blockDim.x;
  for (long i = t * 16; i < n; i += nt * 16) {
    const float4* vp = reinterpret_cast<const float4*>(x + i);
    float4 v0 = vp[0], v1 = vp[1], v2 = vp[2], v3 = vp[3];
    int w0 = 0, w1 = 0, w2 = 0, w3 = 0;
    // IEEE division to match reference t/scale; RNE saturating cvt (OCP e4m3fn)
    w0 = __builtin_amdgcn_cvt_pk_fp8_f32(v0.x / s, v0.y / s, w0, false);
    w0 = __builtin_amdgcn_cvt_pk_fp8_f32(v0.z / s, v0.w / s, w0, true);
    w1 = __builtin_amdgcn_cvt_pk_fp8_f32(v1.x / s, v1.y / s, w1, false);
    w1 = __builtin_amdgcn_cvt_pk_fp8_f32(v1.z / s, v1.w / s, w1, true);
    w2 = __builtin_amdgcn_cvt_pk_fp8_f32(v2.x / s, v2.y / s, w2, false);
    w2 = __builtin_amdgcn_cvt_pk_fp8_f32(v2.z / s, v2.w / s, w2, true);
    w3 = __builtin_amdgcn_cvt_pk_fp8_f32(v3.x / s, v3.y / s, w3, false);
    w3 = __builtin_amdgcn_cvt_pk_fp8_f32(v3.z / s, v3.w / s, w3, true);
    int4 o;
    o.x = w0; o.y = w1; o.z = w2; o.w = w3;
    *reinterpret_cast<int4*>(q + i) = o;
  }
}

// =========================== fp8 GEMM (m97 structure) ===========================
// C[M,N] = sprod * (Aq[M,K] @ Bq[N,K]^T) + bias[N]
// 128x128 tile, BK=64, 256 threads (2x2 waves, 64x64 per wave, 4x4 frags of 16x16)
__global__ __launch_bounds__(256) void gemm_fp8(
    const unsigned char* __restrict__ Aq, const unsigned char* __restrict__ Bq,
    const float* __restrict__ bias, const float* __restrict__ sprod,
    float* __restrict__ C, int M, int N, int K) {
  __shared__ __align__(16) unsigned char As[2 * 4096];  // 128 rows x 64B
  __shared__ __align__(16) unsigned char Bs[2 * 4096];

  const int tid = threadIdx.x;
  const int lane = tid & 63;
  const int wid = tid >> 6;
  const int llo = lane & 15;
  const int lhi = lane >> 4;
  const int wr = wid >> 1, wc = wid & 1;

  // XCD-aware swizzle (bijective: nwg % 8 == 0 for this shape)
  int nwg = gridDim.x;
  int flat = blockIdx.x;
  int swz = flat;
  if ((nwg & 7) == 0) {
    int cpx = nwg >> 3;
    swz = (flat & 7) * cpx + (flat >> 3);
  }
  const int ntn = N >> 7;
  const int tile_m = swz / ntn, tile_n = swz % ntn;
  const int row0 = tile_m << 7, col0 = tile_n << 7;

  // staging: thread t loads 16B at tile-linear offset t*16; LDS dest is
  // wave-uniform base + lane*16 (hardware), matching row*64+col linear layout
  const unsigned char* aptr = Aq + (long)(row0 + (tid >> 2)) * K + (tid & 3) * 16;
  const unsigned char* bptr = Bq + (long)(col0 + (tid >> 2)) * K + (tid & 3) * 16;
  const long rstep = (long)64 * K;

  unsigned char* lA = As + wid * 1024;  // wave-uniform LDS bases
  unsigned char* lB = Bs + wid * 1024;

  f32x4 acc[4][4] = {};

  for (int k0 = 0; k0 < K; k0 += 64) {
    gload_lds16(aptr + k0, lA);
    gload_lds16(aptr + rstep + k0, lA + 4096);
    gload_lds16(bptr + k0, lB);
    gload_lds16(bptr + rstep + k0, lB + 4096);
    __syncthreads();  // compiler drains vmcnt(0) before s_barrier
#pragma unroll
    for (int kk = 0; kk < 2; ++kk) {
      const int kb = kk * 32 + lhi * 8;
      long long af[4], bf[4];
#pragma unroll
      for (int m = 0; m < 4; ++m)
        af[m] = *reinterpret_cast<const long long*>(
            As + (wr * 64 + m * 16 + llo) * 64 + kb);
#pragma unroll
      for (int n = 0; n < 4; ++n)
        bf[n] = *reinterpret_cast<const long long*>(
            Bs + (wc * 64 + n * 16 + llo) * 64 + kb);
#pragma unroll
      for (int m = 0; m < 4; ++m)
#pragma unroll
        for (int n = 0; n < 4; ++n)
          acc[m][n] = __builtin_amdgcn_mfma_f32_16x16x32_fp8_fp8(
              af[m], bf[n], acc[m][n], 0, 0, 0);
    }
    __syncthreads();
  }

  // epilogue: C = acc * (sx*sw) + bias
  const float s = sprod[0];
  float bv[4];
#pragma unroll
  for (int n = 0; n < 4; ++n) bv[n] = bias[col0 + wc * 64 + n * 16 + llo];
#pragma unroll
  for (int m = 0; m < 4; ++m) {
    const int r0 = row0 + wr * 64 + m * 16 + lhi * 4;  // C/D: row=(lane>>4)*4+reg
#pragma unroll
    for (int n = 0; n < 4; ++n) {
      const int c = col0 + wc * 64 + n * 16 + llo;  // col = lane&15
      float* cp = C + (long)r0 * N + c;
#pragma unroll
      for (int r = 0; r < 4; ++r) cp[(long)r * N] = acc[m][n][r] * s + bv[n];
    }
  }
}

// =========================== launch ===========================
extern "C" void kernel_launch(void* const* d_in, const int* in_sizes, int n_in,
                              void* d_out, int out_size, void* d_ws,
                              size_t ws_size, hipStream_t stream) {
  const float* x = (const float*)d_in[0];  // [B,S,Din] = [8192, 4096] flat
  const float* W = (const float*)d_in[1];  // [Dout, Din] = [4096, 4096]
  const float* b = (const float*)d_in[2];  // [Dout]
  float* out = (float*)d_out;              // [8192, 4096] fp32

  const long nx = in_sizes[0];
  const long nw = in_sizes[1];
  const int DIN = 4096;
  const int DOUT = in_sizes[2];  // 4096
  const int M = (int)(nx / DIN); // 8192

  // workspace layout
  unsigned* amax = (unsigned*)d_ws;                  // 2 uints
  float* scales = (float*)((char*)d_ws + 64);        // sx, sw, sx*sw
  unsigned char* xq = (unsigned char*)d_ws + 1024;   // nx bytes
  unsigned char* wq = xq + nx;                       // nw bytes

  hipMemsetAsync(d_ws, 0, 8, stream);  // zero amax slots (ws is 0xAA-poisoned)

  amax_kernel<<<2048, 256, 0, stream>>>(x, nx, amax + 0);
  amax_kernel<<<2048, 256, 0, stream>>>(W, nw, amax + 1);
  scale_kernel<<<1, 1, 0, stream>>>(amax, scales);
  quant_kernel<<<2048, 256, 0, stream>>>(x, xq, nx, scales + 0);
  quant_kernel<<<2048, 256, 0, stream>>>(W, wq, nw, scales + 1);

  dim3 grid((M / 128) * (DOUT / 128));  // 64 * 32 = 2048 blocks
  gemm_fp8<<<grid, 256, 0, stream>>>(xq, wq, b, scales + 2, out, M, DOUT, DIN);
}

// Round 4
// 591.876 us; speedup vs baseline: 1.3564x; 1.3564x over previous
//
#include <hip/hip_runtime.h>
#include <stdint.h>

typedef float f32x4 __attribute__((ext_vector_type(4)));

// ---- async global->LDS, 16B per lane; LDS dest must be wave-uniform base ----
__device__ __forceinline__ void gload_lds16(const void* g, void* l) {
  __builtin_amdgcn_global_load_lds(
      (const __attribute__((address_space(1))) unsigned int*)g,
      (__attribute__((address_space(3))) unsigned int*)l,
      16, 0, 0);
}

// =========================== fused amax reduction ===========================
// blocks [0,gx) reduce x -> out[0]; blocks [gx, grid) reduce W -> out[1]
__global__ void amax2_kernel(const float* __restrict__ x, long nx,
                             const float* __restrict__ W, long nw,
                             unsigned* __restrict__ out, int gx) {
  const float* src;
  long n;
  unsigned* o;
  long bid = blockIdx.x, nb;
  if (blockIdx.x < (unsigned)gx) {
    src = x; n = nx; o = out; nb = gx;
  } else {
    src = W; n = nw; o = out + 1; nb = (long)gridDim.x - gx; bid -= gx;
  }
  long tid = bid * blockDim.x + threadIdx.x;
  long stride = nb * blockDim.x;
  float m = 0.0f;
  for (long i = tid * 4; i < n; i += stride * 4) {
    float4 v = *reinterpret_cast<const float4*>(src + i);
    m = fmaxf(m, fmaxf(fmaxf(fabsf(v.x), fabsf(v.y)),
                       fmaxf(fabsf(v.z), fabsf(v.w))));
  }
#pragma unroll
  for (int off = 32; off > 0; off >>= 1) m = fmaxf(m, __shfl_xor(m, off));
  __shared__ float red[4];
  int wid = threadIdx.x >> 6;
  if ((threadIdx.x & 63) == 0) red[wid] = m;
  __syncthreads();
  if (threadIdx.x == 0) {
    float mm = fmaxf(fmaxf(red[0], red[1]), fmaxf(red[2], red[3]));
    atomicMax(o, __float_as_uint(mm));  // abs fp32: uint order == float order
  }
}

// =========================== scale compute ===========================
__global__ void scale_kernel(const unsigned* __restrict__ amax_bits,
                             float* __restrict__ scales) {
  float ax = __uint_as_float(amax_bits[0]);
  float aw = __uint_as_float(amax_bits[1]);
  float sx = fmaxf(ax, 1e-12f) / 448.0f;  // IEEE div, matches reference
  float sw = fmaxf(aw, 1e-12f) / 448.0f;
  scales[0] = sx;
  scales[1] = sw;
  scales[2] = sx * sw;
}

// =========================== fused quantize to fp8 e4m3 ===========================
__global__ void quant2_kernel(const float* __restrict__ x,
                              unsigned char* __restrict__ qx, long nx,
                              const float* __restrict__ W,
                              unsigned char* __restrict__ qw, long nw,
                              const float* __restrict__ scales, int gx) {
  const float* src;
  unsigned char* q;
  long n;
  float s;
  long bid = blockIdx.x, nb;
  if (blockIdx.x < (unsigned)gx) {
    src = x; q = qx; n = nx; s = scales[0]; nb = gx;
  } else {
    src = W; q = qw; n = nw; s = scales[1];
    nb = (long)gridDim.x - gx; bid -= gx;
  }
  long t = bid * blockDim.x + threadIdx.x;
  long nt = nb * blockDim.x;
  for (long i = t * 16; i < n; i += nt * 16) {
    const float4* vp = reinterpret_cast<const float4*>(src + i);
    float4 v0 = vp[0], v1 = vp[1], v2 = vp[2], v3 = vp[3];
    int w0 = 0, w1 = 0, w2 = 0, w3 = 0;
    // IEEE division to match reference t/scale; RNE saturating cvt (OCP e4m3fn)
    w0 = __builtin_amdgcn_cvt_pk_fp8_f32(v0.x / s, v0.y / s, w0, false);
    w0 = __builtin_amdgcn_cvt_pk_fp8_f32(v0.z / s, v0.w / s, w0, true);
    w1 = __builtin_amdgcn_cvt_pk_fp8_f32(v1.x / s, v1.y / s, w1, false);
    w1 = __builtin_amdgcn_cvt_pk_fp8_f32(v1.z / s, v1.w / s, w1, true);
    w2 = __builtin_amdgcn_cvt_pk_fp8_f32(v2.x / s, v2.y / s, w2, false);
    w2 = __builtin_amdgcn_cvt_pk_fp8_f32(v2.z / s, v2.w / s, w2, true);
    w3 = __builtin_amdgcn_cvt_pk_fp8_f32(v3.x / s, v3.y / s, w3, false);
    w3 = __builtin_amdgcn_cvt_pk_fp8_f32(v3.z / s, v3.w / s, w3, true);
    int4 o;
    o.x = w0; o.y = w1; o.z = w2; o.w = w3;
    *reinterpret_cast<int4*>(q + i) = o;
  }
}

// =========================== fp8 GEMM (m97 structure + chunk-XOR LDS swizzle) ====
// C[M,N] = sprod * (Aq[M,K] @ Bq[N,K]^T) + bias[N]
// 128x128 tile, BK=64, 256 threads (2x2 waves, 64x64 per wave, 4x4 frags of 16x16).
// LDS swizzle: 16B chunk c of row r lives at slot (c ^ (r&3)) within the row.
//  - read:  ds_read_b64 banks = 16(r&1)+8((r>>1)&1)+0..7 -> 16 rows cover each
//    bank exactly 4x = data-rate limit, no excess conflict (was 8-way).
//  - stage: global_load_lds writes linearly, so lane L pre-permutes its GLOBAL
//    chunk: c = (L&3) ^ ((L>>2)&3) (rule #21: source-permute + read-permute).
__global__ __launch_bounds__(256) void gemm_fp8(
    const unsigned char* __restrict__ Aq, const unsigned char* __restrict__ Bq,
    const float* __restrict__ bias, const float* __restrict__ sprod,
    float* __restrict__ C, int M, int N, int K) {
  __shared__ __align__(16) unsigned char As[2 * 4096];  // 128 rows x 64B
  __shared__ __align__(16) unsigned char Bs[2 * 4096];

  const int tid = threadIdx.x;
  const int lane = tid & 63;
  const int wid = tid >> 6;
  const int llo = lane & 15;
  const int lhi = lane >> 4;
  const int wr = wid >> 1, wc = wid & 1;

  // XCD-aware swizzle (bijective: nwg % 8 == 0 for this shape)
  int nwg = gridDim.x;
  int flat = blockIdx.x;
  int swz = flat;
  if ((nwg & 7) == 0) {
    int cpx = nwg >> 3;
    swz = (flat & 7) * cpx + (flat >> 3);
  }
  const int ntn = N >> 7;
  const int tile_m = swz / ntn, tile_n = swz % ntn;
  const int row0 = tile_m << 7, col0 = tile_n << 7;

  // staging: thread t covers tile row (t>>2), global chunk (t&3)^((t>>2)&3)
  const int schunk = (tid & 3) ^ ((tid >> 2) & 3);
  const unsigned char* aptr = Aq + (long)(row0 + (tid >> 2)) * K + schunk * 16;
  const unsigned char* bptr = Bq + (long)(col0 + (tid >> 2)) * K + schunk * 16;
  const long rstep = (long)64 * K;

  unsigned char* lA = As + wid * 1024;  // wave-uniform LDS bases
  unsigned char* lB = Bs + wid * 1024;

  // fragment-read LDS offsets (row*64 + swizzled chunk + half), loop-invariant
  // row&3 == llo&3 for all m/n since tile row = w*64 + m*16 + llo
  const int rxor = llo & 3;
  const int half8 = (lhi & 1) * 8;
  int aoff[4], boff[4];
#pragma unroll
  for (int m = 0; m < 4; ++m)
    aoff[m] = (wr * 64 + m * 16 + llo) * 64 + half8;
#pragma unroll
  for (int n = 0; n < 4; ++n)
    boff[n] = (wc * 64 + n * 16 + llo) * 64 + half8;

  f32x4 acc[4][4] = {};

  for (int k0 = 0; k0 < K; k0 += 64) {
    gload_lds16(aptr + k0, lA);
    gload_lds16(aptr + rstep + k0, lA + 4096);
    gload_lds16(bptr + k0, lB);
    gload_lds16(bptr + rstep + k0, lB + 4096);
    __syncthreads();  // compiler drains vmcnt(0) before s_barrier
#pragma unroll
    for (int kk = 0; kk < 2; ++kk) {
      const int kchunk = kk * 2 + (lhi >> 1);
      const int coff = ((kchunk ^ rxor) * 16);
      long long af[4], bf[4];
#pragma unroll
      for (int m = 0; m < 4; ++m)
        af[m] = *reinterpret_cast<const long long*>(As + aoff[m] + coff);
#pragma unroll
      for (int n = 0; n < 4; ++n)
        bf[n] = *reinterpret_cast<const long long*>(Bs + boff[n] + coff);
#pragma unroll
      for (int m = 0; m < 4; ++m)
#pragma unroll
        for (int n = 0; n < 4; ++n)
          acc[m][n] = __builtin_amdgcn_mfma_f32_16x16x32_fp8_fp8(
              af[m], bf[n], acc[m][n], 0, 0, 0);
    }
    __syncthreads();
  }

  // epilogue: C = acc * (sx*sw) + bias
  const float s = sprod[0];
  float bv[4];
#pragma unroll
  for (int n = 0; n < 4; ++n) bv[n] = bias[col0 + wc * 64 + n * 16 + llo];
#pragma unroll
  for (int m = 0; m < 4; ++m) {
    const int r0 = row0 + wr * 64 + m * 16 + lhi * 4;  // C/D: row=(lane>>4)*4+reg
#pragma unroll
    for (int n = 0; n < 4; ++n) {
      const int c = col0 + wc * 64 + n * 16 + llo;  // col = lane&15
      float* cp = C + (long)r0 * N + c;
#pragma unroll
      for (int r = 0; r < 4; ++r) cp[(long)r * N] = acc[m][n][r] * s + bv[n];
    }
  }
}

// =========================== launch ===========================
extern "C" void kernel_launch(void* const* d_in, const int* in_sizes, int n_in,
                              void* d_out, int out_size, void* d_ws,
                              size_t ws_size, hipStream_t stream) {
  const float* x = (const float*)d_in[0];  // [B,S,Din] = [8192, 4096] flat
  const float* W = (const float*)d_in[1];  // [Dout, Din] = [4096, 4096]
  const float* b = (const float*)d_in[2];  // [Dout]
  float* out = (float*)d_out;              // [8192, 4096] fp32

  const long nx = in_sizes[0];
  const long nw = in_sizes[1];
  const int DIN = 4096;
  const int DOUT = in_sizes[2];  // 4096
  const int M = (int)(nx / DIN); // 8192

  // workspace layout
  unsigned* amax = (unsigned*)d_ws;                  // 2 uints
  float* scales = (float*)((char*)d_ws + 64);        // sx, sw, sx*sw
  unsigned char* xq = (unsigned char*)d_ws + 1024;   // nx bytes
  unsigned char* wq = xq + nx;                       // nw bytes

  hipMemsetAsync(d_ws, 0, 8, stream);  // zero amax slots (ws is 0xAA-poisoned)

  // x is 2x the bytes of W -> give it ~2/3 of the blocks
  amax2_kernel<<<2048, 256, 0, stream>>>(x, nx, W, nw, amax, 1408);
  scale_kernel<<<1, 1, 0, stream>>>(amax, scales);
  quant2_kernel<<<2048, 256, 0, stream>>>(x, xq, nx, W, wq, nw, scales, 1408);

  dim3 grid((M / 128) * (DOUT / 128));  // 64 * 32 = 2048 blocks
  gemm_fp8<<<grid, 256, 0, stream>>>(xq, wq, b, scales + 2, out, M, DOUT, DIN);
}